// Round 11
// baseline (176.569 us; speedup 1.0000x reference)
//
#include <hip/hip_runtime.h>
#include <hip/hip_bf16.h>
#include <cstddef>

#define N_NODES 50000
#define N_EDGES_RAW 800000
#define E_TOT (N_EDGES_RAW + N_NODES) /* 850000 */
#define DIM 128
#define NEG_SLOPE 0.2f

#define NBUCK 196            /* ceil(50000/256) buckets of 256 nodes */
#define CHUNK 4096           /* edges per block in bucket passes */
#define NBLK_E ((E_TOT + CHUNK - 1) / CHUNK) /* 208 */
#define CONV_BLKS 3125       /* 6.4M f32 -> bf16, 2048 elems/block */
#define GB 782               /* gemm blocks: ceil(3125 tiles / 4 waves) */
#define ECHUNK 512           /* edges per node_agg LDS chunk */

typedef __attribute__((ext_vector_type(8))) short bf16x8;
typedef __attribute__((ext_vector_type(4))) float f32x4;

// round-to-nearest-even f32 -> bf16 bits
__device__ __forceinline__ ushort f2bf(float f) {
  unsigned u = __float_as_uint(f);
  return (ushort)((u + 0x7FFFu + ((u >> 16) & 1u)) >> 16);
}
__device__ __forceinline__ float bf2f_lo(uint u) {
  return __uint_as_float(u << 16);
}
__device__ __forceinline__ float bf2f_hi(uint u) {
  return __uint_as_float(u & 0xFFFF0000u);
}

// ---------- edge fetch robust to int32 vs int64 storage of edge_index ----------
__device__ __forceinline__ void get_edge(const int* __restrict__ ei, int is64,
                                         int e, int& s, int& d) {
  if (e >= N_EDGES_RAW) { s = e - N_EDGES_RAW; d = s; return; }
  if (is64) {
    s = ei[2 * (size_t)e];
    d = ei[2 * ((size_t)N_EDGES_RAW + (size_t)e)];
  } else {
    s = ei[e];
    d = ei[N_EDGES_RAW + e];
  }
}

__device__ __forceinline__ int detect_inline(const int* __restrict__ ei,
                                             int* sflag) {
  const int t = threadIdx.x;
  if (t < 64) {
    int hi = ei[2 * t + 1];
    unsigned long long b = __ballot(hi != 0);
    if (t == 0) *sflag = (b == 0ULL) ? 1 : 0;
  }
  __syncthreads();
  return *sflag;
}

// ---------- WtX[144][128] bf16 prep ----------
__device__ __forceinline__ void prep_one(const float* __restrict__ w,
                                         const float* __restrict__ atts,
                                         const float* __restrict__ attd,
                                         ushort* __restrict__ wtx,
                                         int H, int idx) {
  const int c = idx >> 7, k = idx & 127;
  const int C = 128 / H;
  float v;
  if (c < 128) {
    v = w[k * 128 + c];
  } else if (c < 128 + H) {
    const int hd = c - 128;
    float s = 0.f;
    for (int j = 0; j < C; ++j) s += w[k * 128 + hd * C + j] * atts[hd * C + j];
    v = s;
  } else if (c < 128 + 2 * H) {
    const int hd = c - 128 - H;
    float s = 0.f;
    for (int j = 0; j < C; ++j) s += w[k * 128 + hd * C + j] * attd[hd * C + j];
    v = s;
  } else {
    v = 0.f;
  }
  wtx[idx] = f2bf(v);
}

// ---------- mega setup: wtx prep | x->bf16 | per-block histogram + pair pack ----
__global__ __launch_bounds__(256) void mega_setup(
    const float* __restrict__ W1, const float* __restrict__ as1,
    const float* __restrict__ ad1, ushort* __restrict__ wtx1,
    const float* __restrict__ W2, const float* __restrict__ as2,
    const float* __restrict__ ad2, ushort* __restrict__ wtx2,
    const float* __restrict__ x, ushort* __restrict__ x_bf,
    const int* __restrict__ ei, int* __restrict__ hist_mat,
    unsigned* __restrict__ pairs) {
  const int b = blockIdx.x, t = threadIdx.x;
  if (b < 72) {
    prep_one(W1, as1, ad1, wtx1, 4, b * 256 + t);
  } else if (b < 144) {
    prep_one(W2, as2, ad2, wtx2, 1, (b - 72) * 256 + t);
  } else if (b < 144 + CONV_BLKS) {
    const int base = (b - 144) * 2048 + t * 8;
    float4 v0 = *(const float4*)(x + base);
    float4 v1 = *(const float4*)(x + base + 4);
    ushort u[8];
    u[0] = f2bf(v0.x); u[1] = f2bf(v0.y); u[2] = f2bf(v0.z); u[3] = f2bf(v0.w);
    u[4] = f2bf(v1.x); u[5] = f2bf(v1.y); u[6] = f2bf(v1.z); u[7] = f2bf(v1.w);
    *(uint4*)(x_bf + base) = *(const uint4*)u;
  } else {
    __shared__ int hist[NBUCK];
    __shared__ int sflag;
    const int cb = b - 144 - CONV_BLKS;
    if (t < NBUCK) hist[t] = 0;
    const int is64 = detect_inline(ei, &sflag);  // has __syncthreads
    __syncthreads();
    const int e0 = cb * CHUNK;
#pragma unroll
    for (int i = 0; i < CHUNK / 256; ++i) {
      int e = e0 + i * 256 + t;
      if (e < E_TOT) {
        int s, d;
        get_edge(ei, is64, e, s, d);
        pairs[e] = (unsigned)s | ((unsigned)d << 16);
        atomicAdd(&hist[d >> 8], 1);
      }
    }
    __syncthreads();
    if (t < NBUCK) hist_mat[cb * NBUCK + t] = hist[t];
  }
}

// ---------- scatter with self-computed deterministic bases (no global atomics) --
__global__ __launch_bounds__(256) void bucket_scatter(
    const unsigned* __restrict__ pairs, const int* __restrict__ hist_mat,
    unsigned* __restrict__ tmp, int* __restrict__ bstart_g) {
  __shared__ int wtot[4];
  __shared__ int sbase[NBUCK];
  __shared__ int shist[NBUCK];
  const int b = blockIdx.x, t = threadIdx.x, lane = t & 63, wid = t >> 6;
  int tot = 0, pre = 0;
  if (t < NBUCK) {
    for (int bb = 0; bb < NBLK_E; ++bb) {
      int v = hist_mat[bb * NBUCK + t];
      pre += (bb < b) ? v : 0;
      tot += v;
    }
    shist[t] = 0;
  }
  int sc = tot;
#pragma unroll
  for (int m = 1; m < 64; m <<= 1) {
    int o = __shfl_up(sc, m, 64);
    if (lane >= m) sc += o;
  }
  if (lane == 63) wtot[wid] = sc;
  __syncthreads();
  int off = 0;
  for (int w = 0; w < wid; ++w) off += wtot[w];
  const int excl = off + sc - tot;
  if (t < NBUCK) sbase[t] = excl + pre;
  if (b == 0) {
    if (t < NBUCK) bstart_g[t] = excl;
    if (t == 255) bstart_g[NBUCK] = off + sc;
  }
  __syncthreads();
  const int e0 = b * CHUNK;
  unsigned pr_[CHUNK / 256];
  int rk[CHUNK / 256];
#pragma unroll
  for (int i = 0; i < CHUNK / 256; ++i) {
    int e = e0 + i * 256 + t;
    if (e < E_TOT) {
      unsigned pr = pairs[e];
      pr_[i] = pr;
      rk[i] = atomicAdd(&shist[pr >> 24], 1);
    }
  }
#pragma unroll
  for (int i = 0; i < CHUNK / 256; ++i) {
    int e = e0 + i * 256 + t;
    if (e < E_TOT) tmp[sbase[pr_[i] >> 24] + rk[i]] = pr_[i];
  }
}

// ---------- per-bucket counting sort body (emits PACKED (s|d<<16) csr) --------
__device__ __forceinline__ void bucket_sort_body(int b,
                                                 const unsigned* __restrict__ tmp,
                                                 const int* __restrict__ bstart,
                                                 unsigned* __restrict__ csr2,
                                                 int* __restrict__ rp,
                                                 int* __restrict__ deg) {
  __shared__ int cnt[256];
  __shared__ int cur[256];
  __shared__ int wtot2[4];
  const int t = threadIdx.x, lane = t & 63, wid = t >> 6;
  const int p0 = bstart[b], p1 = bstart[b + 1];
  cnt[t] = 0;
  __syncthreads();
  for (int j = p0 + t; j < p1; j += 256) {
    unsigned pr = tmp[j];
    atomicAdd(&cnt[(pr >> 16) & 255u], 1);
  }
  __syncthreads();
  int v = cnt[t];
  int sc = v;
#pragma unroll
  for (int m = 1; m < 64; m <<= 1) {
    int o = __shfl_up(sc, m, 64);
    if (lane >= m) sc += o;
  }
  if (lane == 63) wtot2[wid] = sc;
  __syncthreads();
  int off = 0;
  for (int w = 0; w < wid; ++w) off += wtot2[w];
  const int excl = off + sc - v;
  const int node = b * 256 + t;
  if (node < N_NODES) {
    deg[node] = v;
    rp[node] = p0 + excl;
  }
  cur[t] = excl;
  __syncthreads();
  for (int j = p0 + t; j < p1; j += 256) {
    unsigned pr = tmp[j];
    int ld = (int)((pr >> 16) & 255u);
    int r = atomicAdd(&cur[ld], 1);
    csr2[p0 + r] = pr;  // keep full (s | d<<16)
  }
}

// ---------- MFMA GEMM body (bf16 in) + fused attention-score columns ----------
template <int H>
__device__ __forceinline__ void gemm_att_body(int blk,
                                              const ushort* __restrict__ in_bf,
                                              const ushort* __restrict__ wtx,
                                              ushort* __restrict__ h_bf,
                                              float* __restrict__ a_src,
                                              float* __restrict__ a_dst) {
  const int wid = threadIdx.x >> 6;
  const int lane = threadIdx.x & 63;
  const int tile = blk * 4 + wid;
  if (tile >= N_NODES / 16) return;
  const int row0 = tile * 16;
  const int rA = lane & 15;
  const int g = lane >> 4;

  f32x4 acc[9];
#pragma unroll
  for (int ct = 0; ct < 9; ++ct) acc[ct] = (f32x4){0.f, 0.f, 0.f, 0.f};

#pragma unroll
  for (int ks = 0; ks < 4; ++ks) {
    const int k0 = ks * 32 + g * 8;
    bf16x8 af = *(const bf16x8*)(in_bf + (size_t)(row0 + rA) * DIM + k0);
#pragma unroll
    for (int ct = 0; ct < 9; ++ct) {
      bf16x8 bf = *(const bf16x8*)(wtx + (size_t)(ct * 16 + rA) * 128 + k0);
      acc[ct] = __builtin_amdgcn_mfma_f32_16x16x32_bf16(af, bf, acc[ct], 0, 0, 0);
    }
  }

#pragma unroll
  for (int ct = 0; ct < 8; ++ct) {
#pragma unroll
    for (int r = 0; r < 4; ++r) {
      const int row = row0 + g * 4 + r;
      h_bf[(size_t)row * DIM + ct * 16 + rA] = f2bf(acc[ct][r]);
    }
  }
  if (rA < 2 * H) {
#pragma unroll
    for (int r = 0; r < 4; ++r) {
      const int row = row0 + g * 4 + r;
      if (rA < H)
        a_src[(size_t)row * H + rA] = acc[8][r];
      else
        a_dst[(size_t)row * H + (rA - H)] = acc[8][r];
    }
  }
}

// ---------- fused: gemm_att<4> (blocks 0..GB-1) || bucket_sort (blocks GB..) ----
__global__ __launch_bounds__(256) void gemm4_sort(
    const ushort* __restrict__ x_bf, const ushort* __restrict__ wtx1,
    ushort* __restrict__ h_bf, float* __restrict__ a_src,
    float* __restrict__ a_dst, const unsigned* __restrict__ tmp,
    const int* __restrict__ bstart, unsigned* __restrict__ csr2,
    int* __restrict__ rp, int* __restrict__ deg) {
  if (blockIdx.x < GB)
    gemm_att_body<4>(blockIdx.x, x_bf, wtx1, h_bf, a_src, a_dst);
  else
    bucket_sort_body(blockIdx.x - GB, tmp, bstart, csr2, rp, deg);
}

// ---------- standalone gemm_att<1> for layer 2 ----------
__global__ __launch_bounds__(256) void gemm_att1(const ushort* __restrict__ in_bf,
                                                 const ushort* __restrict__ wtx,
                                                 ushort* __restrict__ h_bf,
                                                 float* __restrict__ a_src,
                                                 float* __restrict__ a_dst) {
  gemm_att_body<1>(blockIdx.x, in_bf, wtx, h_bf, a_src, a_dst);
}

// ---------- block-cooperative softmax + gather + bias + relu ------------------
// Block owns 16 consecutive nodes (contiguous sorted edge range).
// Phase A: 256 threads score 1 edge each (coalesced pair read, 256-way MLP on
//          random a_src[s]) -> p_lds[j][H] (conflict-free: H consecutive words),
//          s_lds[j].
// Phase B: wave handles 4 nodes serially; 2 feats/lane; per edge: 2 broadcast
//          LDS reads + 1 row load + 2 FMA; sden accumulated per-lane (no shfl).
template <int H, bool OBF>
__global__ __launch_bounds__(256) void node_agg(const int* __restrict__ rp,
                                                const int* __restrict__ deg,
                                                const unsigned* __restrict__ csr2,
                                                const ushort* __restrict__ h_bf,
                                                const float* __restrict__ a_src,
                                                const float* __restrict__ a_dst,
                                                const float* __restrict__ bias,
                                                void* __restrict__ outp) {
  __shared__ float p_lds[ECHUNK][H];
  __shared__ int s_lds[ECHUNK];
  const int t = threadIdx.x;
  const int wid = t >> 6;
  const int lane = t & 63;
  const int nbase = blockIdx.x * 16;
  const int head = (H == 4) ? (lane >> 4) : 0;  // lane owns features 2*lane..+1

  // wave's 4 nodes
  int rp_m[4], dg_m[4];
#pragma unroll
  for (int m = 0; m < 4; ++m) {
    int n = nbase + 4 * wid + m;
    rp_m[m] = rp[n];
    dg_m[m] = deg[n];
  }
  const int blockbase = rp[nbase];
  const int blockend = rp[nbase + 15] + deg[nbase + 15];

  float ax[4], ay[4], sden[4];
#pragma unroll
  for (int m = 0; m < 4; ++m) { ax[m] = 0.f; ay[m] = 0.f; sden[m] = 0.f; }

  for (int base = blockbase; base < blockend; base += ECHUNK) {
    const int cnt = min(ECHUNK, blockend - base);
    // ---- phase A: one edge per thread ----
    for (int k = t; k < cnt; k += 256) {
      unsigned pr = csr2[base + k];
      int s = (int)(pr & 0xFFFFu);
      int d = (int)(pr >> 16);
      s_lds[k] = s;
      if (H == 4) {
        float4 as4 = ((const float4*)a_src)[s];
        float4 ad4 = ((const float4*)a_dst)[d];
        float vv[4] = {as4.x + ad4.x, as4.y + ad4.y, as4.z + ad4.z, as4.w + ad4.w};
#pragma unroll
        for (int h = 0; h < 4; ++h) {
          float v = vv[h];
          v = v > 0.f ? v : NEG_SLOPE * v;
          v = fminf(fmaxf(v, -60.f), 80.f);
          p_lds[k][h] = __expf(v);
        }
      } else {
        float v = a_src[s] + a_dst[d];
        v = v > 0.f ? v : NEG_SLOPE * v;
        v = fminf(fmaxf(v, -60.f), 80.f);
        p_lds[k][0] = __expf(v);
      }
    }
    __syncthreads();
    // ---- phase B: each wave aggregates its 4 nodes ----
#pragma unroll
    for (int m = 0; m < 4; ++m) {
      const int lo = max(rp_m[m], base) - base;
      const int hi = min(rp_m[m] + dg_m[m], base + cnt) - base;
#pragma unroll 2
      for (int j = lo; j < hi; ++j) {
        int s = s_lds[j];
        float p = p_lds[j][head];
        uint hv = *(const uint*)(h_bf + (size_t)s * DIM + 2 * lane);
        ax[m] += p * bf2f_lo(hv);
        ay[m] += p * bf2f_hi(hv);
        sden[m] += p;
      }
    }
    __syncthreads();
  }

  const float2 bv = ((const float2*)bias)[lane];
#pragma unroll
  for (int m = 0; m < 4; ++m) {
    const int node = nbase + 4 * wid + m;
    const float inv = 1.f / sden[m];
    float ox = fmaxf(ax[m] * inv + bv.x, 0.f);
    float oy = fmaxf(ay[m] * inv + bv.y, 0.f);
    if (OBF) {
      uint u = (uint)f2bf(ox) | ((uint)f2bf(oy) << 16);
      ((uint*)((ushort*)outp + (size_t)node * DIM))[lane] = u;
    } else {
      ((float2*)((float*)outp + (size_t)node * DIM))[lane] = make_float2(ox, oy);
    }
  }
}

extern "C" void kernel_launch(void* const* d_in, const int* in_sizes, int n_in,
                              void* d_out, int out_size, void* d_ws, size_t ws_size,
                              hipStream_t stream) {
  const float* x   = (const float*)d_in[0];
  const int*   ei  = (const int*)d_in[1];
  const float* W1  = (const float*)d_in[2];
  const float* as1 = (const float*)d_in[3];
  const float* ad1 = (const float*)d_in[4];
  const float* b1  = (const float*)d_in[5];
  const float* W2  = (const float*)d_in[6];
  const float* as2 = (const float*)d_in[7];
  const float* ad2 = (const float*)d_in[8];
  const float* b2  = (const float*)d_in[9];
  float* out = (float*)d_out;

  char* ws = (char*)d_ws;
  const size_t F_H = (size_t)N_NODES * DIM;  // 6.4M elems
  ushort*   h_bf    = (ushort*)ws;                    // 12.8 MB
  ushort*   z_bf    = h_bf + F_H;                     // 12.8 MB
  ushort*   x_bf    = z_bf + F_H;                     // 12.8 MB
  float*    a_src   = (float*)(x_bf + F_H);           // 800 KB
  float*    a_dst   = a_src + 200000;                 // 800 KB
  int*      deg     = (int*)(a_dst + 200000);         // 200 KB
  int*      rp      = deg + N_NODES;                  // 200 KB
  unsigned* csr2    = (unsigned*)(rp + N_NODES);      // 3.4 MB (s | d<<16)
  unsigned* tmp     = csr2 + E_TOT;                   // 3.4 MB
  unsigned* pairs   = tmp + E_TOT;                    // 3.4 MB
  int*      hist_mat= (int*)(pairs + E_TOT);          // 163 KB
  int*      bstart  = hist_mat + NBLK_E * NBUCK;      // NBUCK+1
  ushort*   wtx1    = (ushort*)(bstart + NBUCK + 3);  // 36 KB
  ushort*   wtx2    = wtx1 + 144 * 128;               // 36 KB

  const int MEGA = 144 + CONV_BLKS + NBLK_E;  // 3477
  const int AGG_B = N_NODES / 16;             // 3125

  hipLaunchKernelGGL(mega_setup, dim3(MEGA), dim3(256), 0, stream,
                     W1, as1, ad1, wtx1, W2, as2, ad2, wtx2, x, x_bf, ei,
                     hist_mat, pairs);
  hipLaunchKernelGGL(bucket_scatter, dim3(NBLK_E), dim3(256), 0, stream,
                     pairs, hist_mat, tmp, bstart);
  // bucket_sort (196 blocks) runs concurrently with layer-1 GEMM (782 blocks)
  hipLaunchKernelGGL(gemm4_sort, dim3(GB + NBUCK), dim3(256), 0, stream,
                     x_bf, wtx1, h_bf, a_src, a_dst, tmp, bstart, csr2, rp, deg);
  hipLaunchKernelGGL((node_agg<4, true>), dim3(AGG_B), dim3(256), 0, stream,
                     rp, deg, csr2, h_bf, a_src, a_dst, b1, z_bf);

  hipLaunchKernelGGL(gemm_att1, dim3(GB), dim3(256), 0, stream,
                     z_bf, wtx2, h_bf, a_src, a_dst);
  hipLaunchKernelGGL((node_agg<1, false>), dim3(AGG_B), dim3(256), 0, stream,
                     rp, deg, csr2, h_bf, a_src, a_dst, b2, out);
}

// Round 12
// 164.052 us; speedup vs baseline: 1.0763x; 1.0763x over previous
//
#include <hip/hip_runtime.h>
#include <hip/hip_bf16.h>
#include <cstddef>

#define N_NODES 50000
#define N_EDGES_RAW 800000
#define E_TOT (N_EDGES_RAW + N_NODES) /* 850000 */
#define DIM 128
#define NEG_SLOPE 0.2f

#define NBUCK 196            /* ceil(50000/256) buckets of 256 nodes */
#define CHUNK 4096           /* edges per block in bucket passes */
#define NBLK_E ((E_TOT + CHUNK - 1) / CHUNK) /* 208 */
#define CONV_BLKS 3125       /* 6.4M f32 -> bf16, 2048 elems/block */
#define GB 782               /* gemm blocks: ceil(3125 tiles / 4 waves) */

typedef __attribute__((ext_vector_type(8))) short bf16x8;
typedef __attribute__((ext_vector_type(4))) float f32x4;

// round-to-nearest-even f32 -> bf16 bits
__device__ __forceinline__ ushort f2bf(float f) {
  unsigned u = __float_as_uint(f);
  return (ushort)((u + 0x7FFFu + ((u >> 16) & 1u)) >> 16);
}
__device__ __forceinline__ float bf2f_lo(uint u) {
  return __uint_as_float(u << 16);
}
__device__ __forceinline__ float bf2f_hi(uint u) {
  return __uint_as_float(u & 0xFFFF0000u);
}

// ---------- edge fetch robust to int32 vs int64 storage of edge_index ----------
__device__ __forceinline__ void get_edge(const int* __restrict__ ei, int is64,
                                         int e, int& s, int& d) {
  if (e >= N_EDGES_RAW) { s = e - N_EDGES_RAW; d = s; return; }
  if (is64) {
    s = ei[2 * (size_t)e];
    d = ei[2 * ((size_t)N_EDGES_RAW + (size_t)e)];
  } else {
    s = ei[e];
    d = ei[N_EDGES_RAW + e];
  }
}

__device__ __forceinline__ int detect_inline(const int* __restrict__ ei,
                                             int* sflag) {
  const int t = threadIdx.x;
  if (t < 64) {
    int hi = ei[2 * t + 1];
    unsigned long long b = __ballot(hi != 0);
    if (t == 0) *sflag = (b == 0ULL) ? 1 : 0;
  }
  __syncthreads();
  return *sflag;
}

// ---------- WtX[144][128] bf16 prep ----------
__device__ __forceinline__ void prep_one(const float* __restrict__ w,
                                         const float* __restrict__ atts,
                                         const float* __restrict__ attd,
                                         ushort* __restrict__ wtx,
                                         int H, int idx) {
  const int c = idx >> 7, k = idx & 127;
  const int C = 128 / H;
  float v;
  if (c < 128) {
    v = w[k * 128 + c];
  } else if (c < 128 + H) {
    const int hd = c - 128;
    float s = 0.f;
    for (int j = 0; j < C; ++j) s += w[k * 128 + hd * C + j] * atts[hd * C + j];
    v = s;
  } else if (c < 128 + 2 * H) {
    const int hd = c - 128 - H;
    float s = 0.f;
    for (int j = 0; j < C; ++j) s += w[k * 128 + hd * C + j] * attd[hd * C + j];
    v = s;
  } else {
    v = 0.f;
  }
  wtx[idx] = f2bf(v);
}

// ---------- mega setup: wtx prep | x->bf16 | per-block histogram + pair pack ----
__global__ __launch_bounds__(256) void mega_setup(
    const float* __restrict__ W1, const float* __restrict__ as1,
    const float* __restrict__ ad1, ushort* __restrict__ wtx1,
    const float* __restrict__ W2, const float* __restrict__ as2,
    const float* __restrict__ ad2, ushort* __restrict__ wtx2,
    const float* __restrict__ x, ushort* __restrict__ x_bf,
    const int* __restrict__ ei, int* __restrict__ hist_mat,
    unsigned* __restrict__ pairs) {
  const int b = blockIdx.x, t = threadIdx.x;
  if (b < 72) {
    prep_one(W1, as1, ad1, wtx1, 4, b * 256 + t);
  } else if (b < 144) {
    prep_one(W2, as2, ad2, wtx2, 1, (b - 72) * 256 + t);
  } else if (b < 144 + CONV_BLKS) {
    const int base = (b - 144) * 2048 + t * 8;
    float4 v0 = *(const float4*)(x + base);
    float4 v1 = *(const float4*)(x + base + 4);
    ushort u[8];
    u[0] = f2bf(v0.x); u[1] = f2bf(v0.y); u[2] = f2bf(v0.z); u[3] = f2bf(v0.w);
    u[4] = f2bf(v1.x); u[5] = f2bf(v1.y); u[6] = f2bf(v1.z); u[7] = f2bf(v1.w);
    *(uint4*)(x_bf + base) = *(const uint4*)u;
  } else {
    __shared__ int hist[NBUCK];
    __shared__ int sflag;
    const int cb = b - 144 - CONV_BLKS;
    if (t < NBUCK) hist[t] = 0;
    const int is64 = detect_inline(ei, &sflag);  // has __syncthreads
    __syncthreads();
    const int e0 = cb * CHUNK;
#pragma unroll
    for (int i = 0; i < CHUNK / 256; ++i) {
      int e = e0 + i * 256 + t;
      if (e < E_TOT) {
        int s, d;
        get_edge(ei, is64, e, s, d);
        pairs[e] = (unsigned)s | ((unsigned)d << 16);
        atomicAdd(&hist[d >> 8], 1);
      }
    }
    __syncthreads();
    if (t < NBUCK) hist_mat[cb * NBUCK + t] = hist[t];
  }
}

// ---------- scatter with self-computed deterministic bases (no global atomics) --
__global__ __launch_bounds__(256) void bucket_scatter(
    const unsigned* __restrict__ pairs, const int* __restrict__ hist_mat,
    unsigned* __restrict__ tmp, int* __restrict__ bstart_g) {
  __shared__ int wtot[4];
  __shared__ int sbase[NBUCK];
  __shared__ int shist[NBUCK];
  const int b = blockIdx.x, t = threadIdx.x, lane = t & 63, wid = t >> 6;
  int tot = 0, pre = 0;
  if (t < NBUCK) {
    for (int bb = 0; bb < NBLK_E; ++bb) {
      int v = hist_mat[bb * NBUCK + t];
      pre += (bb < b) ? v : 0;
      tot += v;
    }
    shist[t] = 0;
  }
  int sc = tot;
#pragma unroll
  for (int m = 1; m < 64; m <<= 1) {
    int o = __shfl_up(sc, m, 64);
    if (lane >= m) sc += o;
  }
  if (lane == 63) wtot[wid] = sc;
  __syncthreads();
  int off = 0;
  for (int w = 0; w < wid; ++w) off += wtot[w];
  const int excl = off + sc - tot;
  if (t < NBUCK) sbase[t] = excl + pre;
  if (b == 0) {
    if (t < NBUCK) bstart_g[t] = excl;
    if (t == 255) bstart_g[NBUCK] = off + sc;
  }
  __syncthreads();
  const int e0 = b * CHUNK;
  unsigned pr_[CHUNK / 256];
  int rk[CHUNK / 256];
#pragma unroll
  for (int i = 0; i < CHUNK / 256; ++i) {
    int e = e0 + i * 256 + t;
    if (e < E_TOT) {
      unsigned pr = pairs[e];
      pr_[i] = pr;
      rk[i] = atomicAdd(&shist[pr >> 24], 1);
    }
  }
#pragma unroll
  for (int i = 0; i < CHUNK / 256; ++i) {
    int e = e0 + i * 256 + t;
    if (e < E_TOT) tmp[sbase[pr_[i] >> 24] + rk[i]] = pr_[i];
  }
}

// ---------- per-bucket counting sort body (emits PACKED (s|d<<16) csr) --------
__device__ __forceinline__ void bucket_sort_body(int b,
                                                 const unsigned* __restrict__ tmp,
                                                 const int* __restrict__ bstart,
                                                 unsigned* __restrict__ csr2,
                                                 int* __restrict__ rp,
                                                 int* __restrict__ deg) {
  __shared__ int cnt[256];
  __shared__ int cur[256];
  __shared__ int wtot2[4];
  const int t = threadIdx.x, lane = t & 63, wid = t >> 6;
  const int p0 = bstart[b], p1 = bstart[b + 1];
  cnt[t] = 0;
  __syncthreads();
  for (int j = p0 + t; j < p1; j += 256) {
    unsigned pr = tmp[j];
    atomicAdd(&cnt[(pr >> 16) & 255u], 1);
  }
  __syncthreads();
  int v = cnt[t];
  int sc = v;
#pragma unroll
  for (int m = 1; m < 64; m <<= 1) {
    int o = __shfl_up(sc, m, 64);
    if (lane >= m) sc += o;
  }
  if (lane == 63) wtot2[wid] = sc;
  __syncthreads();
  int off = 0;
  for (int w = 0; w < wid; ++w) off += wtot2[w];
  const int excl = off + sc - v;
  const int node = b * 256 + t;
  if (node < N_NODES) {
    deg[node] = v;
    rp[node] = p0 + excl;
  }
  cur[t] = excl;
  __syncthreads();
  for (int j = p0 + t; j < p1; j += 256) {
    unsigned pr = tmp[j];
    int ld = (int)((pr >> 16) & 255u);
    int r = atomicAdd(&cur[ld], 1);
    csr2[p0 + r] = pr;  // keep full (s | d<<16)
  }
}

// ---------- MFMA GEMM body (bf16 in) + fused attention-score columns ----------
template <int H>
__device__ __forceinline__ void gemm_att_body(int blk,
                                              const ushort* __restrict__ in_bf,
                                              const ushort* __restrict__ wtx,
                                              ushort* __restrict__ h_bf,
                                              float* __restrict__ a_src,
                                              float* __restrict__ a_dst) {
  const int wid = threadIdx.x >> 6;
  const int lane = threadIdx.x & 63;
  const int tile = blk * 4 + wid;
  if (tile >= N_NODES / 16) return;
  const int row0 = tile * 16;
  const int rA = lane & 15;
  const int g = lane >> 4;

  f32x4 acc[9];
#pragma unroll
  for (int ct = 0; ct < 9; ++ct) acc[ct] = (f32x4){0.f, 0.f, 0.f, 0.f};

#pragma unroll
  for (int ks = 0; ks < 4; ++ks) {
    const int k0 = ks * 32 + g * 8;
    bf16x8 af = *(const bf16x8*)(in_bf + (size_t)(row0 + rA) * DIM + k0);
#pragma unroll
    for (int ct = 0; ct < 9; ++ct) {
      bf16x8 bf = *(const bf16x8*)(wtx + (size_t)(ct * 16 + rA) * 128 + k0);
      acc[ct] = __builtin_amdgcn_mfma_f32_16x16x32_bf16(af, bf, acc[ct], 0, 0, 0);
    }
  }

#pragma unroll
  for (int ct = 0; ct < 8; ++ct) {
#pragma unroll
    for (int r = 0; r < 4; ++r) {
      const int row = row0 + g * 4 + r;
      h_bf[(size_t)row * DIM + ct * 16 + rA] = f2bf(acc[ct][r]);
    }
  }
  if (rA < 2 * H) {
#pragma unroll
    for (int r = 0; r < 4; ++r) {
      const int row = row0 + g * 4 + r;
      if (rA < H)
        a_src[(size_t)row * H + rA] = acc[8][r];
      else
        a_dst[(size_t)row * H + (rA - H)] = acc[8][r];
    }
  }
}

// ---------- fused: gemm_att<4> (blocks 0..GB-1) || bucket_sort (blocks GB..) ----
__global__ __launch_bounds__(256) void gemm4_sort(
    const ushort* __restrict__ x_bf, const ushort* __restrict__ wtx1,
    ushort* __restrict__ h_bf, float* __restrict__ a_src,
    float* __restrict__ a_dst, const unsigned* __restrict__ tmp,
    const int* __restrict__ bstart, unsigned* __restrict__ csr2,
    int* __restrict__ rp, int* __restrict__ deg) {
  if (blockIdx.x < GB)
    gemm_att_body<4>(blockIdx.x, x_bf, wtx1, h_bf, a_src, a_dst);
  else
    bucket_sort_body(blockIdx.x - GB, tmp, bstart, csr2, rp, deg);
}

// ---------- standalone gemm_att<1> for layer 2 ----------
__global__ __launch_bounds__(256) void gemm_att1(const ushort* __restrict__ in_bf,
                                                 const ushort* __restrict__ wtx,
                                                 ushort* __restrict__ h_bf,
                                                 float* __restrict__ a_src,
                                                 float* __restrict__ a_dst) {
  gemm_att_body<1>(blockIdx.x, in_bf, wtx, h_bf, a_src, a_dst);
}

// ---------- fused single-pass softmax + gather + bias + relu (phase A/B) ------
// Wave per node (max MLP: 50K independent waves). Phase A: up to 64 edges scored
// one-per-lane (each (edge,head) exactly once) -> p_lds / s_lds. Phase B: 2
// feats/lane, 1 edge/iter, no score dependency, unroll 8; sden accumulated
// per-lane in phase B (lane's head fixed) -> NO cross-lane reduce at all.
// LDS layout p_lds[wid][H][68]: read addr head*272+j*4 -> 4 distinct banks
// (conflict-free broadcast); write addr h*272+lane*4 -> 2 lanes/bank (free).
template <int H, bool OBF>
__global__ __launch_bounds__(256) void node_agg(const int* __restrict__ rp,
                                                const int* __restrict__ deg,
                                                const unsigned* __restrict__ csr2,
                                                const ushort* __restrict__ h_bf,
                                                const float* __restrict__ a_src,
                                                const float* __restrict__ a_dst,
                                                const float* __restrict__ bias,
                                                void* __restrict__ outp) {
  __shared__ float p_lds[4][H][68];
  __shared__ int s_lds[4][64];
  const int wid = threadIdx.x >> 6;
  const int lane = threadIdx.x & 63;
  const int node = blockIdx.x * 4 + wid;
  if (node >= N_NODES) return;
  const int head = (H == 4) ? (lane >> 4) : 0;  // lane owns features 2*lane..+1
  const int beg = rp[node];
  const int dg = deg[node];

  float ad[H];
#pragma unroll
  for (int h = 0; h < H; ++h) ad[h] = a_dst[(size_t)node * H + h];

  float sden = 0.f, ax = 0.f, ay = 0.f;

  for (int c0 = 0; c0 < dg; c0 += 64) {
    const int cnt = min(64, dg - c0);
    // ---- phase A: one edge per lane ----
    if (lane < cnt) {
      int s = (int)(csr2[beg + c0 + lane] & 0xFFFFu);
      s_lds[wid][lane] = s;
      if (H == 4) {
        float4 as4 = ((const float4*)a_src)[s];
        float vv[4] = {as4.x, as4.y, as4.z, as4.w};
#pragma unroll
        for (int h = 0; h < 4; ++h) {
          float v = vv[h] + ad[h];
          v = v > 0.f ? v : NEG_SLOPE * v;
          v = fminf(fmaxf(v, -60.f), 80.f);
          p_lds[wid][h][lane] = __expf(v);
        }
      } else {
        float v = a_src[s] + ad[0];
        v = v > 0.f ? v : NEG_SLOPE * v;
        v = fminf(fmaxf(v, -60.f), 80.f);
        p_lds[wid][0][lane] = __expf(v);
      }
    }
    // same-wave LDS RAW: compiler inserts lgkmcnt waits; no __syncthreads needed
    // ---- phase B: 2 features/lane, independent iterations ----
    int j = 0;
    for (; j + 8 <= cnt; j += 8) {
#pragma unroll
      for (int u = 0; u < 8; ++u) {
        int s = s_lds[wid][j + u];
        float p = p_lds[wid][head][j + u];
        uint hv = *(const uint*)(h_bf + (size_t)s * DIM + 2 * lane);
        ax += p * bf2f_lo(hv);
        ay += p * bf2f_hi(hv);
        sden += p;
      }
    }
    for (; j < cnt; ++j) {
      int s = s_lds[wid][j];
      float p = p_lds[wid][head][j];
      uint hv = *(const uint*)(h_bf + (size_t)s * DIM + 2 * lane);
      ax += p * bf2f_lo(hv);
      ay += p * bf2f_hi(hv);
      sden += p;
    }
  }

  const float inv = 1.f / sden;  // deg >= 1 (self-loop), all lanes summed all p
  float2 bv = ((const float2*)bias)[lane];
  float ox = fmaxf(ax * inv + bv.x, 0.f);
  float oy = fmaxf(ay * inv + bv.y, 0.f);
  if (OBF) {
    uint u = (uint)f2bf(ox) | ((uint)f2bf(oy) << 16);
    ((uint*)((ushort*)outp + (size_t)node * DIM))[lane] = u;
  } else {
    ((float2*)((float*)outp + (size_t)node * DIM))[lane] = make_float2(ox, oy);
  }
}

extern "C" void kernel_launch(void* const* d_in, const int* in_sizes, int n_in,
                              void* d_out, int out_size, void* d_ws, size_t ws_size,
                              hipStream_t stream) {
  const float* x   = (const float*)d_in[0];
  const int*   ei  = (const int*)d_in[1];
  const float* W1  = (const float*)d_in[2];
  const float* as1 = (const float*)d_in[3];
  const float* ad1 = (const float*)d_in[4];
  const float* b1  = (const float*)d_in[5];
  const float* W2  = (const float*)d_in[6];
  const float* as2 = (const float*)d_in[7];
  const float* ad2 = (const float*)d_in[8];
  const float* b2  = (const float*)d_in[9];
  float* out = (float*)d_out;

  char* ws = (char*)d_ws;
  const size_t F_H = (size_t)N_NODES * DIM;  // 6.4M elems
  ushort*   h_bf    = (ushort*)ws;                    // 12.8 MB
  ushort*   z_bf    = h_bf + F_H;                     // 12.8 MB
  ushort*   x_bf    = z_bf + F_H;                     // 12.8 MB
  float*    a_src   = (float*)(x_bf + F_H);           // 800 KB
  float*    a_dst   = a_src + 200000;                 // 800 KB
  int*      deg     = (int*)(a_dst + 200000);         // 200 KB
  int*      rp      = deg + N_NODES;                  // 200 KB
  unsigned* csr2    = (unsigned*)(rp + N_NODES);      // 3.4 MB (s | d<<16)
  unsigned* tmp     = csr2 + E_TOT;                   // 3.4 MB
  unsigned* pairs   = tmp + E_TOT;                    // 3.4 MB
  int*      hist_mat= (int*)(pairs + E_TOT);          // 163 KB
  int*      bstart  = hist_mat + NBLK_E * NBUCK;      // NBUCK+1
  ushort*   wtx1    = (ushort*)(bstart + NBUCK + 3);  // 36 KB
  ushort*   wtx2    = wtx1 + 144 * 128;               // 36 KB

  const int MEGA = 144 + CONV_BLKS + NBLK_E;  // 3477
  const int AGG_B = (N_NODES + 3) / 4;        // 12500

  hipLaunchKernelGGL(mega_setup, dim3(MEGA), dim3(256), 0, stream,
                     W1, as1, ad1, wtx1, W2, as2, ad2, wtx2, x, x_bf, ei,
                     hist_mat, pairs);
  hipLaunchKernelGGL(bucket_scatter, dim3(NBLK_E), dim3(256), 0, stream,
                     pairs, hist_mat, tmp, bstart);
  // bucket_sort (196 blocks) runs concurrently with layer-1 GEMM (782 blocks)
  hipLaunchKernelGGL(gemm4_sort, dim3(GB + NBUCK), dim3(256), 0, stream,
                     x_bf, wtx1, h_bf, a_src, a_dst, tmp, bstart, csr2, rp, deg);
  hipLaunchKernelGGL((node_agg<4, true>), dim3(AGG_B), dim3(256), 0, stream,
                     rp, deg, csr2, h_bf, a_src, a_dst, b1, z_bf);

  hipLaunchKernelGGL(gemm_att1, dim3(GB), dim3(256), 0, stream,
                     z_bf, wtx2, h_bf, a_src, a_dst);
  hipLaunchKernelGGL((node_agg<1, false>), dim3(AGG_B), dim3(256), 0, stream,
                     rp, deg, csr2, h_bf, a_src, a_dst, b2, out);
}